// Round 6
// baseline (505.916 us; speedup 1.0000x reference)
//
#include <hip/hip_runtime.h>
#include <hip/hip_bf16.h>

// MHA forward: B=4, S=1024, E=1024, H=16, HD=64.
// d_out: out (B,S,E)=4194304 fp32, then attn (B,H,S,S)=67108864 fp32.
// ws (bf16): Xq/Xk/Xv 3x4M, Wq/Wk/Wv/Wo 4x1M, Qb/Kb (B*S,E) 2x4M,
//            Vt (B*H,HD,S) 4M, Ob (B*S,E) 4M  => 32M elems = 64 MB.

typedef short bf16x8 __attribute__((ext_vector_type(8)));
typedef float f32x4 __attribute__((ext_vector_type(4)));

#define VMCNT(n) asm volatile("s_waitcnt vmcnt(" #n ")" ::: "memory")

__device__ __forceinline__ unsigned short f2bf(float f) {
  union { float f; unsigned u; } v; v.f = f;
  unsigned r = v.u + 0x7FFF + ((v.u >> 16) & 1);   // RNE; finite inputs
  return (unsigned short)(r >> 16);
}

__device__ __forceinline__ float bf2f(unsigned short u) {
  union { unsigned u; float f; } v; v.u = ((unsigned)u) << 16;
  return v.f;
}

// async global->LDS, 16B per lane; LDS dest = wave-uniform base + lane*16 (m97/m104)
__device__ __forceinline__ void gload16(const unsigned short* g, unsigned short* l) {
  __builtin_amdgcn_global_load_lds(
      (const __attribute__((address_space(1))) unsigned int*)g,
      (__attribute__((address_space(3))) unsigned int*)l, 16, 0, 0);
}

// ---------------- casts (fp32 -> bf16), 8 elems/thread ----------------
__global__ __launch_bounds__(256) void cast3_k(
    const float* __restrict__ a, const float* __restrict__ b,
    const float* __restrict__ c,
    unsigned short* __restrict__ oa, unsigned short* __restrict__ ob,
    unsigned short* __restrict__ oc) {
  const float* in = blockIdx.y == 0 ? a : blockIdx.y == 1 ? b : c;
  unsigned short* out = blockIdx.y == 0 ? oa : blockIdx.y == 1 ? ob : oc;
  int i = (blockIdx.x * 256 + threadIdx.x) * 8;
  float4 x = *(const float4*)(in + i);
  float4 y = *(const float4*)(in + i + 4);
  unsigned short t[8] = { f2bf(x.x), f2bf(x.y), f2bf(x.z), f2bf(x.w),
                          f2bf(y.x), f2bf(y.y), f2bf(y.z), f2bf(y.w) };
  *(bf16x8*)(out + i) = *(bf16x8*)t;
}

__global__ __launch_bounds__(256) void cast4_k(
    const float* __restrict__ a, const float* __restrict__ b,
    const float* __restrict__ c, const float* __restrict__ d,
    unsigned short* __restrict__ oa, unsigned short* __restrict__ ob,
    unsigned short* __restrict__ oc, unsigned short* __restrict__ od) {
  const float* in = blockIdx.y == 0 ? a : blockIdx.y == 1 ? b : blockIdx.y == 2 ? c : d;
  unsigned short* out = blockIdx.y == 0 ? oa : blockIdx.y == 1 ? ob : blockIdx.y == 2 ? oc : od;
  int i = (blockIdx.x * 256 + threadIdx.x) * 8;
  float4 x = *(const float4*)(in + i);
  float4 y = *(const float4*)(in + i + 4);
  unsigned short t[8] = { f2bf(x.x), f2bf(x.y), f2bf(x.z), f2bf(x.w),
                          f2bf(y.x), f2bf(y.y), f2bf(y.z), f2bf(y.w) };
  *(bf16x8*)(out + i) = *(bf16x8*)t;
}

// ---------------- GEMM core: 128x128 tile, BK=64, global_load_lds + XOR swizzle ----
__device__ __forceinline__ void gemm_core(
    const unsigned short* __restrict__ A, const unsigned short* __restrict__ W,
    int m0, int n0, int K, unsigned short* As, unsigned short* Bs, f32x4 acc[4][4])
{
  const int tid = threadIdx.x;
  const int w = tid >> 6, lane = tid & 63, quad = lane >> 4, lc = lane & 15;
  const int wm = (w >> 1) * 64, wn = (w & 1) * 64;
  const int lrow = lane >> 3, lg = lane & 7;

  for (int kb = 0; kb < K; kb += 64) {
#pragma unroll
    for (int t = 0; t < 4; t++) {
      int row = w * 32 + t * 8 + lrow;
      int gsw = lg ^ (row & 7);
      gload16(&A[(size_t)(m0 + row) * K + kb + gsw * 8], &As[(w * 32 + t * 8) * 64]);
      gload16(&W[(size_t)(n0 + row) * K + kb + gsw * 8], &Bs[(w * 32 + t * 8) * 64]);
    }
    __syncthreads();
#pragma unroll
    for (int kk = 0; kk < 2; kk++) {
      bf16x8 af[4], bfr[4];
#pragma unroll
      for (int i = 0; i < 4; i++) {
        int ra = wm + i * 16 + lc;
        af[i] = *(const bf16x8*)&As[ra * 64 + (((kk * 4 + quad) ^ (ra & 7)) * 8)];
      }
#pragma unroll
      for (int j = 0; j < 4; j++) {
        int rb = wn + j * 16 + lc;
        bfr[j] = *(const bf16x8*)&Bs[rb * 64 + (((kk * 4 + quad) ^ (rb & 7)) * 8)];
      }
#pragma unroll
      for (int i = 0; i < 4; i++)
#pragma unroll
        for (int j = 0; j < 4; j++)
          acc[i][j] = __builtin_amdgcn_mfma_f32_16x16x32_bf16(af[i], bfr[j], acc[i][j], 0, 0, 0);
    }
    __syncthreads();
  }
}

// QKV projections in one launch (grid.z = 0,1,2). Q/K: bf16 (B*S,E) row-major.
// V: bf16 head-transposed (B*H, HD, S) via LDS transpose epilogue.
__global__ __launch_bounds__(256) void gemm_qkv(
    const unsigned short* __restrict__ Xq, const unsigned short* __restrict__ Xk,
    const unsigned short* __restrict__ Xv,
    const unsigned short* __restrict__ Wq, const unsigned short* __restrict__ Wk,
    const unsigned short* __restrict__ Wv,
    const float* __restrict__ bq, const float* __restrict__ bk, const float* __restrict__ bv,
    unsigned short* __restrict__ Qb, unsigned short* __restrict__ Kb,
    unsigned short* __restrict__ Vt)
{
  __shared__ __align__(16) unsigned short S[128 * 136];
  unsigned short* As = S;
  unsigned short* Bs = S + 128 * 64;
  const int z = blockIdx.z;
  const unsigned short* A = z == 0 ? Xq : z == 1 ? Xk : Xv;
  const unsigned short* W = z == 0 ? Wq : z == 1 ? Wk : Wv;
  const float* bias = z == 0 ? bq : z == 1 ? bk : bv;
  unsigned short* outRM = z == 0 ? Qb : Kb;
  const int m0 = blockIdx.x * 128, n0 = blockIdx.y * 128;
  const int tid = threadIdx.x;
  const int w = tid >> 6, lane = tid & 63, quad = lane >> 4, lc = lane & 15;
  const int wm = (w >> 1) * 64, wn = (w & 1) * 64;

  f32x4 acc[4][4] = {};
  gemm_core(A, W, m0, n0, 1024, As, Bs, acc);

  if (z < 2) {
#pragma unroll
    for (int j = 0; j < 4; j++) {
      int col = n0 + wn + j * 16 + lc;
      float bvl = bias[col];
#pragma unroll
      for (int i = 0; i < 4; i++)
#pragma unroll
        for (int r = 0; r < 4; r++) {
          int row = m0 + wm + i * 16 + quad * 4 + r;
          outRM[(size_t)row * 1024 + col] = f2bf(acc[i][j][r] + bvl);
        }
    }
  } else {
    // gemm_core's trailing barrier guarantees As/Bs reads are done -> reuse as T.
    unsigned short* T = S;
#pragma unroll
    for (int j = 0; j < 4; j++) {
      int col = wn + j * 16 + lc;              // local col (output E dim)
      float bvl = bias[n0 + col];
#pragma unroll
      for (int i = 0; i < 4; i++)
#pragma unroll
        for (int r = 0; r < 4; r++) {
          int row = wm + i * 16 + quad * 4 + r;  // local row (token s)
          T[col * 136 + (((row >> 3) ^ (col & 7)) << 3) + (row & 7)] =
              f2bf(acc[i][j][r] + bvl);
        }
    }
    __syncthreads();
    const int b_ = m0 >> 10, sb = m0 & 1023;
#pragma unroll
    for (int it = 0; it < 8; it++) {
      int cl = w * 32 + it * 4 + (lane >> 4);  // local col 0..127
      int sg = lane & 15;                      // s-granule (8 tokens)
      int colg = n0 + cl;
      *(bf16x8*)&Vt[((size_t)((b_ * 16 + (colg >> 6)) * 64 + (colg & 63))) * 1024 + sb + sg * 8] =
          *(const bf16x8*)&T[cl * 136 + ((sg ^ (cl & 7)) << 3)];
    }
  }
}

// Final projection: O(bf16) @ Wo^T + bo -> fp32 out.
__global__ __launch_bounds__(256) void gemm_out(
    const unsigned short* __restrict__ A, const unsigned short* __restrict__ W,
    const float* __restrict__ bias, float* __restrict__ outf)
{
  __shared__ __align__(16) unsigned short As[128 * 64];
  __shared__ __align__(16) unsigned short Bs[128 * 64];
  const int m0 = blockIdx.x * 128, n0 = blockIdx.y * 128;
  const int tid = threadIdx.x;
  const int w = tid >> 6, lane = tid & 63, quad = lane >> 4, lc = lane & 15;
  const int wm = (w >> 1) * 64, wn = (w & 1) * 64;

  f32x4 acc[4][4] = {};
  gemm_core(A, W, m0, n0, 1024, As, Bs, acc);

#pragma unroll
  for (int j = 0; j < 4; j++) {
    int col = n0 + wn + j * 16 + lc;
    float bvl = bias[col];
#pragma unroll
    for (int i = 0; i < 4; i++)
#pragma unroll
      for (int r = 0; r < 4; r++) {
        int row = m0 + wm + i * 16 + quad * 4 + r;
        outf[(size_t)row * 1024 + col] = acc[i][j][r] + bvl;
      }
  }
}

// ---------------- fused attention: two-pass flash, dbuf K/V, ONE barrier/chunk ----
// grid (B*H=64, S/64=16), 4 waves; wave owns 16 q-rows.
// r2-proven body (per-tile online softmax, no setprio, no VGPR cap, heavy-first by)
// + the two clean r5 pieces: one-barrier-per-chunk dbuf schedule and NT attn stores.
// Schedule per chunk c: vmcnt(chunk-c loads) -> s_barrier -> issue prefetch c+1 ->
// compute c. The barrier proves all waves finished chunk c-1's reads, so prefetch
// (targeting buf[(c+1)&1], last read in c-1) can't race. Counted vmcnt in pass B:
// first chunk 0, then 4 (the 4 prefetch loads always precede the <=4 NT stores in
// issue order -- pinned by sched_barrier(0) -- and vmcnt retires in issue order).
__global__ __launch_bounds__(256) void attn_fused(
    const unsigned short* __restrict__ Qb,   // (B*S,E) bf16
    const unsigned short* __restrict__ Kb,   // (B*S,E) bf16
    const unsigned short* __restrict__ Vt,   // (B*H,HD,S) bf16
    float* __restrict__ attn,                // (B*H,S,S) fp32
    unsigned short* __restrict__ O)          // (B*S,E) bf16
{
  __shared__ __align__(16) unsigned short Ks[2][64 * 64];  // 16 KB
  __shared__ __align__(16) unsigned short Vs[2][64 * 64];  // 16 KB
  __shared__ __align__(16) unsigned short Pl[4][16][40];   // 5 KB per-wave bf16 P
  const int bh = blockIdx.x, b = bh >> 4, h = bh & 15;
  const int by = (int)gridDim.y - 1 - (int)blockIdx.y;     // heavy blocks dispatch first
  const int q0 = by * 64;
  const int tid = threadIdx.x;
  const int w = tid >> 6, lane = tid & 63, quad = lane >> 4, lc = lane & 15;
  const int g0 = q0 + w * 16;
  const int kt_d = g0 >> 4;                  // wave's diagonal 16-tile index = 4*by + w
  const int nch = by + 1;                    // 64-kv chunks (block-uniform)
  const int sr = lane >> 3, sg = lane & 7;
  const int r0_ = w * 8 + sr, r1_ = 32 + r0_;

  // Q fragment, pre-scaled by 1/8 (exact in bf16: exponent shift).
  bf16x8 a0, a1;
  {
    const unsigned short* qp = Qb + ((size_t)(b * 1024 + g0 + lc)) * 1024 + h * 64 + quad * 8;
    bf16x8 q0v = *(const bf16x8*)qp;
    bf16x8 q1v = *(const bf16x8*)(qp + 32);
#pragma unroll
    for (int i = 0; i < 8; i++) {
      a0[i] = (short)f2bf(bf2f((unsigned short)q0v[i]) * 0.125f);
      a1[i] = (short)f2bf(bf2f((unsigned short)q1v[i]) * 0.125f);
    }
  }

  float m_[4] = { -1e30f, -1e30f, -1e30f, -1e30f };
  float l_[4] = { 0.f, 0.f, 0.f, 0.f };

  // ---- pass A: online stats; K dbuf, one barrier per chunk ----
  gload16(&Kb[((size_t)(b * 1024 + r0_)) * 1024 + h * 64 + (sg ^ (r0_ & 7)) * 8],
          &Ks[0][(w * 8) * 64]);
  gload16(&Kb[((size_t)(b * 1024 + r1_)) * 1024 + h * 64 + (sg ^ (r1_ & 7)) * 8],
          &Ks[0][(32 + w * 8) * 64]);
  for (int c = 0; c < nch; c++) {
    const unsigned short* Kc = Ks[c & 1];
    int kv0 = c * 64;
    VMCNT(0);                                // pass A has no stores: chunk-c loads done
    __builtin_amdgcn_s_barrier();
    __builtin_amdgcn_sched_barrier(0);
    if (c + 1 < nch) {
      int nv0 = kv0 + 64;
      unsigned short* Kn = Ks[(c + 1) & 1];
      gload16(&Kb[((size_t)(b * 1024 + nv0 + r0_)) * 1024 + h * 64 + (sg ^ (r0_ & 7)) * 8],
              &Kn[(w * 8) * 64]);
      gload16(&Kb[((size_t)(b * 1024 + nv0 + r1_)) * 1024 + h * 64 + (sg ^ (r1_ & 7)) * 8],
              &Kn[(32 + w * 8) * 64]);
    }
    __builtin_amdgcn_sched_barrier(0);
    int tmax = kt_d - c * 4;                 // >= 0 always (c <= by, kt_d >= 4*by+w)
    int tlim = tmax < 3 ? tmax : 3;
    for (int t = 0; t <= tlim; t++) {
      int rk = t * 16 + lc;
      const unsigned short* kr = &Kc[rk * 64];
      bf16x8 b0 = *(const bf16x8*)&kr[((quad ^ (rk & 7))) * 8];
      bf16x8 b1 = *(const bf16x8*)&kr[(((quad + 4) ^ (rk & 7))) * 8];
      f32x4 c0 = {}, c1 = {};
      c0 = __builtin_amdgcn_mfma_f32_16x16x32_bf16(a0, b0, c0, 0, 0, 0);
      c1 = __builtin_amdgcn_mfma_f32_16x16x32_bf16(a1, b1, c1, 0, 0, 0);
      if (t < tmax) {                        // strictly below diagonal: no mask needed
#pragma unroll
        for (int r = 0; r < 4; r++) {
          float s = c0[r] + c1[r];
          float mn = fmaxf(m_[r], s);
          l_[r] = l_[r] * __expf(m_[r] - mn) + __expf(s - mn);
          m_[r] = mn;
        }
      } else {                               // diagonal tile: apply causal mask
#pragma unroll
        for (int r = 0; r < 4; r++) {
          int qr = g0 + quad * 4 + r;
          float sv = (kv0 + t * 16 + lc) > qr ? -1e30f : c0[r] + c1[r];
          float mn = fmaxf(m_[r], sv);
          l_[r] = l_[r] * __expf(m_[r] - mn) + __expf(sv - mn);
          m_[r] = mn;
        }
      }
    }
  }

  // one cross-lane reduction per row group (16 lanes share a row)
  float mofs[4];
#pragma unroll
  for (int r = 0; r < 4; r++) {
    float mT = m_[r];
#pragma unroll
    for (int off = 1; off < 16; off <<= 1) mT = fmaxf(mT, __shfl_xor(mT, off));
    float lt = l_[r] * __expf(m_[r] - mT);
#pragma unroll
    for (int off = 1; off < 16; off <<= 1) lt += __shfl_xor(lt, off);
    mofs[r] = mT + __logf(lt);               // p = exp(s - m - ln l)
  }

  // transition barrier: all pass-A reads done before pass-B prologue DMA hits Ks[0]
  __builtin_amdgcn_s_barrier();
  __builtin_amdgcn_sched_barrier(0);

  // ---- pass B: recompute, normalize, NT attn stores from Pl, PV ----
  float* arow = attn + (size_t)bh * 1024 * 1024;
  f32x4 oacc[4] = {};
  gload16(&Kb[((size_t)(b * 1024 + r0_)) * 1024 + h * 64 + (sg ^ (r0_ & 7)) * 8],
          &Ks[0][(w * 8) * 64]);
  gload16(&Kb[((size_t)(b * 1024 + r1_)) * 1024 + h * 64 + (sg ^ (r1_ & 7)) * 8],
          &Ks[0][(32 + w * 8) * 64]);
  gload16(&Vt[((size_t)(bh * 64 + r0_)) * 1024 + (sg ^ (r0_ & 7)) * 8],
          &Vs[0][(w * 8) * 64]);
  gload16(&Vt[((size_t)(bh * 64 + r1_)) * 1024 + (sg ^ (r1_ & 7)) * 8],
          &Vs[0][(32 + w * 8) * 64]);
  for (int c = 0; c < nch; c++) {
    const unsigned short* Kc = Ks[c & 1];
    const unsigned short* Vc = Vs[c & 1];
    int kv0 = c * 64;
    // wait chunk-c loads (issued before last iter's <=4 NT stores; in-order retire)
    if (c == 0) { VMCNT(0); } else { VMCNT(4); }
    __builtin_amdgcn_s_barrier();
    __builtin_amdgcn_sched_barrier(0);
    if (c + 1 < nch) {
      int nv0 = kv0 + 64;
      unsigned short* Kn = Ks[(c + 1) & 1];
      unsigned short* Vn = Vs[(c + 1) & 1];
      gload16(&Kb[((size_t)(b * 1024 + nv0 + r0_)) * 1024 + h * 64 + (sg ^ (r0_ & 7)) * 8],
              &Kn[(w * 8) * 64]);
      gload16(&Kb[((size_t)(b * 1024 + nv0 + r1_)) * 1024 + h * 64 + (sg ^ (r1_ & 7)) * 8],
              &Kn[(32 + w * 8) * 64]);
      gload16(&Vt[((size_t)(bh * 64 + r0_)) * 1024 + nv0 + (sg ^ (r0_ & 7)) * 8],
              &Vn[(w * 8) * 64]);
      gload16(&Vt[((size_t)(bh * 64 + r1_)) * 1024 + nv0 + (sg ^ (r1_ & 7)) * 8],
              &Vn[(32 + w * 8) * 64]);
    }
    // pin issue order: prefetch loads precede this chunk's NT stores, so the
    // counted VMCNT at the next loop top is exact.
    __builtin_amdgcn_sched_barrier(0);
    int tmax = kt_d - c * 4;
#pragma unroll
    for (int u = 0; u < 2; u++) {
      if (u * 2 <= tmax) {                   // wave-uniform
#pragma unroll
        for (int t2 = 0; t2 < 2; t2++) {
          int t = u * 2 + t2;
          if (t <= tmax) {                   // wave-uniform
            int rk = t * 16 + lc;
            const unsigned short* kr = &Kc[rk * 64];
            bf16x8 b0 = *(const bf16x8*)&kr[((quad ^ (rk & 7))) * 8];
            bf16x8 b1 = *(const bf16x8*)&kr[(((quad + 4) ^ (rk & 7))) * 8];
            f32x4 c0 = {}, c1 = {};
            c0 = __builtin_amdgcn_mfma_f32_16x16x32_bf16(a0, b0, c0, 0, 0, 0);
            c1 = __builtin_amdgcn_mfma_f32_16x16x32_bf16(a1, b1, c1, 0, 0, 0);
#pragma unroll
            for (int r = 0; r < 4; r++) {
              int qr = g0 + quad * 4 + r;
              float p = (kv0 + t * 16 + lc) > qr ? 0.f
                        : __expf(c0[r] + c1[r] - mofs[r]);
              Pl[w][quad * 4 + r][t2 * 16 + lc] = f2bf(p);
            }
          } else {
#pragma unroll
            for (int r = 0; r < 4; r++) Pl[w][quad * 4 + r][t2 * 16 + lc] = 0;
          }
        }
        // NT attn stores: 16 rows x 32 cols fp32 from Pl (128B/row segments)
        {
          int srow = lane >> 2, c4 = lane & 3;
          bf16x8 pv8 = *(const bf16x8*)&Pl[w][srow][c4 * 8];
          f32x4 f0, f1;
          f0[0] = bf2f((unsigned short)pv8[0]); f0[1] = bf2f((unsigned short)pv8[1]);
          f0[2] = bf2f((unsigned short)pv8[2]); f0[3] = bf2f((unsigned short)pv8[3]);
          f1[0] = bf2f((unsigned short)pv8[4]); f1[1] = bf2f((unsigned short)pv8[5]);
          f1[2] = bf2f((unsigned short)pv8[6]); f1[3] = bf2f((unsigned short)pv8[7]);
          float* dst = &arow[(size_t)(g0 + srow) * 1024 + kv0 + u * 32 + c4 * 8];
          __builtin_nontemporal_store(f0, (f32x4*)dst);
          __builtin_nontemporal_store(f1, (f32x4*)(dst + 4));
        }
        // PV over this 32-kv sub-chunk
        bf16x8 pa = *(const bf16x8*)&Pl[w][lc][quad * 8];
#pragma unroll
        for (int j = 0; j < 4; j++) {
          int hd = j * 16 + lc;
          bf16x8 bv = *(const bf16x8*)&Vc[hd * 64 + (((u * 4 + quad) ^ (hd & 7)) * 8)];
          oacc[j] = __builtin_amdgcn_mfma_f32_16x16x32_bf16(pa, bv, oacc[j], 0, 0, 0);
        }
      }
    }
  }

  // ---- zero-fill fully-masked region [g0+16, 1024) for the wave's 16 rows ----
  {
    int rr = lane >> 2, cl = lane & 3;
    f32x4 z = { 0.f, 0.f, 0.f, 0.f };
    for (int c0 = g0 + 16 + cl * 4; c0 < 1024; c0 += 16)
      __builtin_nontemporal_store(z, (f32x4*)&arow[(size_t)(g0 + rr) * 1024 + c0]);
  }

  // ---- store O (B*S,E) bf16 via LDS bounce (16B stores, 128B row segments) ----
  __syncthreads();                           // all PV reads done before Ks reuse
  {
    unsigned short* ob = &Ks[0][0] + w * 1152;           // 16 rows x 72-short stride
#pragma unroll
    for (int j = 0; j < 4; j++)
#pragma unroll
      for (int r = 0; r < 4; r++)
        ob[(quad * 4 + r) * 72 + j * 16 + lc] = f2bf(oacc[j][r]);
#pragma unroll
    for (int it = 0; it < 2; it++) {
      int row = it * 8 + (lane >> 3), off = (lane & 7) * 8;
      *(bf16x8*)&O[((size_t)(b * 1024 + g0 + row)) * 1024 + h * 64 + off] =
          *(const bf16x8*)&ob[row * 72 + off];
    }
  }
}

extern "C" void kernel_launch(void* const* d_in, const int* in_sizes, int n_in,
                              void* d_out, int out_size, void* d_ws, size_t ws_size,
                              hipStream_t stream) {
  const float* query = (const float*)d_in[0];
  const float* key_t = (const float*)d_in[1];
  const float* value = (const float*)d_in[2];
  // d_in[3] = mask: causal tril, applied analytically
  const float* Wq = (const float*)d_in[4];
  const float* bq = (const float*)d_in[5];
  const float* Wk = (const float*)d_in[6];
  const float* bk = (const float*)d_in[7];
  const float* Wv = (const float*)d_in[8];
  const float* bv = (const float*)d_in[9];
  const float* Wo = (const float*)d_in[10];
  const float* bo = (const float*)d_in[11];

  unsigned short* Xq  = (unsigned short*)d_ws;
  unsigned short* Xk  = Xq  + 4194304;
  unsigned short* Xv  = Xk  + 4194304;
  unsigned short* Wqb = Xv  + 4194304;
  unsigned short* Wkb = Wqb + 1048576;
  unsigned short* Wvb = Wkb + 1048576;
  unsigned short* Wob = Wvb + 1048576;
  unsigned short* Qb  = Wob + 1048576;
  unsigned short* Kb  = Qb  + 4194304;
  unsigned short* Vtb = Kb  + 4194304;
  unsigned short* Ob  = Vtb + 4194304;

  float* outO = (float*)d_out;
  float* attn = outO + 4194304;

  cast3_k<<<dim3(2048, 3), 256, 0, stream>>>(query, key_t, value, Xq, Xk, Xv);
  cast4_k<<<dim3(512, 4), 256, 0, stream>>>(Wq, Wk, Wv, Wo, Wqb, Wkb, Wvb, Wob);

  gemm_qkv<<<dim3(32, 8, 3), 256, 0, stream>>>(Xq, Xk, Xv, Wqb, Wkb, Wvb,
                                               bq, bk, bv, Qb, Kb, Vtb);

  attn_fused<<<dim3(64, 16), 256, 0, stream>>>(Qb, Kb, Vtb, attn, Ob);

  gemm_out<<<dim3(32, 8), 256, 0, stream>>>(Ob, Wob, bo, outO);
}

// Round 7
// 469.500 us; speedup vs baseline: 1.0776x; 1.0776x over previous
//
#include <hip/hip_runtime.h>
#include <hip/hip_bf16.h>

// MHA forward: B=4, S=1024, E=1024, H=16, HD=64.
// d_out: out (B,S,E)=4194304 fp32, then attn (B,H,S,S)=67108864 fp32.
// ws (bf16): Xq/Xk/Xv 3x4M, Wq/Wk/Wv/Wo 4x1M, Qb/Kb (B*S,E) 2x4M,
//            Vt (B*H,HD,S) 4M, Ob (B*S,E) 4M  => 32M elems = 64 MB.
// This is the r1-best (482.3us) kernel restored verbatim, with ONE change:
// the attn zero-fill now writes 128B-contiguous segments per row (was 64B).

typedef short bf16x8 __attribute__((ext_vector_type(8)));
typedef float f32x4 __attribute__((ext_vector_type(4)));

__device__ __forceinline__ unsigned short f2bf(float f) {
  union { float f; unsigned u; } v; v.f = f;
  unsigned r = v.u + 0x7FFF + ((v.u >> 16) & 1);   // RNE; finite inputs
  return (unsigned short)(r >> 16);
}

// async global->LDS, 16B per lane; LDS dest = wave-uniform base + lane*16 (m97/m104)
__device__ __forceinline__ void gload16(const unsigned short* g, unsigned short* l) {
  __builtin_amdgcn_global_load_lds(
      (const __attribute__((address_space(1))) unsigned int*)g,
      (__attribute__((address_space(3))) unsigned int*)l, 16, 0, 0);
}

// ---------------- casts (fp32 -> bf16), 8 elems/thread ----------------
__global__ __launch_bounds__(256) void cast3_k(
    const float* __restrict__ a, const float* __restrict__ b,
    const float* __restrict__ c,
    unsigned short* __restrict__ oa, unsigned short* __restrict__ ob,
    unsigned short* __restrict__ oc) {
  const float* in = blockIdx.y == 0 ? a : blockIdx.y == 1 ? b : c;
  unsigned short* out = blockIdx.y == 0 ? oa : blockIdx.y == 1 ? ob : oc;
  int i = (blockIdx.x * 256 + threadIdx.x) * 8;
  float4 x = *(const float4*)(in + i);
  float4 y = *(const float4*)(in + i + 4);
  unsigned short t[8] = { f2bf(x.x), f2bf(x.y), f2bf(x.z), f2bf(x.w),
                          f2bf(y.x), f2bf(y.y), f2bf(y.z), f2bf(y.w) };
  *(bf16x8*)(out + i) = *(bf16x8*)t;
}

__global__ __launch_bounds__(256) void cast4_k(
    const float* __restrict__ a, const float* __restrict__ b,
    const float* __restrict__ c, const float* __restrict__ d,
    unsigned short* __restrict__ oa, unsigned short* __restrict__ ob,
    unsigned short* __restrict__ oc, unsigned short* __restrict__ od) {
  const float* in = blockIdx.y == 0 ? a : blockIdx.y == 1 ? b : blockIdx.y == 2 ? c : d;
  unsigned short* out = blockIdx.y == 0 ? oa : blockIdx.y == 1 ? ob : blockIdx.y == 2 ? oc : od;
  int i = (blockIdx.x * 256 + threadIdx.x) * 8;
  float4 x = *(const float4*)(in + i);
  float4 y = *(const float4*)(in + i + 4);
  unsigned short t[8] = { f2bf(x.x), f2bf(x.y), f2bf(x.z), f2bf(x.w),
                          f2bf(y.x), f2bf(y.y), f2bf(y.z), f2bf(y.w) };
  *(bf16x8*)(out + i) = *(bf16x8*)t;
}

// ---------------- GEMM core: 128x128 tile, BK=64, global_load_lds + XOR swizzle ----
// LDS granule g of row r holds global granule g^(r&7): staging is unpadded
// (global_load_lds requires it) and fragment ds_read_b128 stays 2-way max (free).
__device__ __forceinline__ void gemm_core(
    const unsigned short* __restrict__ A, const unsigned short* __restrict__ W,
    int m0, int n0, int K, unsigned short* As, unsigned short* Bs, f32x4 acc[4][4])
{
  const int tid = threadIdx.x;
  const int w = tid >> 6, lane = tid & 63, quad = lane >> 4, lc = lane & 15;
  const int wm = (w >> 1) * 64, wn = (w & 1) * 64;
  const int lrow = lane >> 3, lg = lane & 7;

  for (int kb = 0; kb < K; kb += 64) {
#pragma unroll
    for (int t = 0; t < 4; t++) {
      int row = w * 32 + t * 8 + lrow;
      int gsw = lg ^ (row & 7);
      gload16(&A[(size_t)(m0 + row) * K + kb + gsw * 8], &As[(w * 32 + t * 8) * 64]);
      gload16(&W[(size_t)(n0 + row) * K + kb + gsw * 8], &Bs[(w * 32 + t * 8) * 64]);
    }
    __syncthreads();
#pragma unroll
    for (int kk = 0; kk < 2; kk++) {
      bf16x8 af[4], bfr[4];
#pragma unroll
      for (int i = 0; i < 4; i++) {
        int ra = wm + i * 16 + lc;
        af[i] = *(const bf16x8*)&As[ra * 64 + (((kk * 4 + quad) ^ (ra & 7)) * 8)];
      }
#pragma unroll
      for (int j = 0; j < 4; j++) {
        int rb = wn + j * 16 + lc;
        bfr[j] = *(const bf16x8*)&Bs[rb * 64 + (((kk * 4 + quad) ^ (rb & 7)) * 8)];
      }
#pragma unroll
      for (int i = 0; i < 4; i++)
#pragma unroll
        for (int j = 0; j < 4; j++)
          acc[i][j] = __builtin_amdgcn_mfma_f32_16x16x32_bf16(af[i], bfr[j], acc[i][j], 0, 0, 0);
    }
    __syncthreads();
  }
}

// QKV projections in one launch (grid.z = 0,1,2). Q/K: bf16 (B*S,E) row-major.
// V: bf16 head-transposed (B*H, HD, S). z==2 epilogue transposes the 128x128 tile
// through LDS so Vt stores are 16B on 256B-contiguous runs (was: 2B scatter @2KB stride).
__global__ __launch_bounds__(256) void gemm_qkv(
    const unsigned short* __restrict__ Xq, const unsigned short* __restrict__ Xk,
    const unsigned short* __restrict__ Xv,
    const unsigned short* __restrict__ Wq, const unsigned short* __restrict__ Wk,
    const unsigned short* __restrict__ Wv,
    const float* __restrict__ bq, const float* __restrict__ bk, const float* __restrict__ bv,
    unsigned short* __restrict__ Qb, unsigned short* __restrict__ Kb,
    unsigned short* __restrict__ Vt)
{
  // S serves as As(8192)+Bs(8192) during gemm_core, and as T[128][136] (transpose
  // buffer, 16B-aligned row stride, granule-XOR swizzled) during the z==2 epilogue.
  __shared__ __align__(16) unsigned short S[128 * 136];
  unsigned short* As = S;
  unsigned short* Bs = S + 128 * 64;
  const int z = blockIdx.z;
  const unsigned short* A = z == 0 ? Xq : z == 1 ? Xk : Xv;
  const unsigned short* W = z == 0 ? Wq : z == 1 ? Wk : Wv;
  const float* bias = z == 0 ? bq : z == 1 ? bk : bv;
  unsigned short* outRM = z == 0 ? Qb : Kb;
  const int m0 = blockIdx.x * 128, n0 = blockIdx.y * 128;
  const int tid = threadIdx.x;
  const int w = tid >> 6, lane = tid & 63, quad = lane >> 4, lc = lane & 15;
  const int wm = (w >> 1) * 64, wn = (w & 1) * 64;

  f32x4 acc[4][4] = {};
  gemm_core(A, W, m0, n0, 1024, As, Bs, acc);

  if (z < 2) {
#pragma unroll
    for (int j = 0; j < 4; j++) {
      int col = n0 + wn + j * 16 + lc;
      float bvl = bias[col];
#pragma unroll
      for (int i = 0; i < 4; i++)
#pragma unroll
        for (int r = 0; r < 4; r++) {
          int row = m0 + wm + i * 16 + quad * 4 + r;
          outRM[(size_t)row * 1024 + col] = f2bf(acc[i][j][r] + bvl);
        }
    }
  } else {
    // gemm_core's trailing barrier guarantees As/Bs reads are done -> reuse as T.
    unsigned short* T = S;
#pragma unroll
    for (int j = 0; j < 4; j++) {
      int col = wn + j * 16 + lc;              // local col (output E dim)
      float bvl = bias[n0 + col];
#pragma unroll
      for (int i = 0; i < 4; i++)
#pragma unroll
        for (int r = 0; r < 4; r++) {
          int row = wm + i * 16 + quad * 4 + r;  // local row (token s)
          // T[col][row] with 8-row granule swizzled by col&7 (bank spread)
          T[col * 136 + (((row >> 3) ^ (col & 7)) << 3) + (row & 7)] =
              f2bf(acc[i][j][r] + bvl);
        }
    }
    __syncthreads();
    const int b_ = m0 >> 10, sb = m0 & 1023;
#pragma unroll
    for (int it = 0; it < 8; it++) {
      int cl = w * 32 + it * 4 + (lane >> 4);  // local col 0..127
      int sg = lane & 15;                      // s-granule (8 tokens)
      int colg = n0 + cl;
      *(bf16x8*)&Vt[((size_t)((b_ * 16 + (colg >> 6)) * 64 + (colg & 63))) * 1024 + sb + sg * 8] =
          *(const bf16x8*)&T[cl * 136 + ((sg ^ (cl & 7)) << 3)];
    }
  }
}

// Final projection: O(bf16) @ Wo^T + bo -> fp32 out.
__global__ __launch_bounds__(256) void gemm_out(
    const unsigned short* __restrict__ A, const unsigned short* __restrict__ W,
    const float* __restrict__ bias, float* __restrict__ outf)
{
  __shared__ __align__(16) unsigned short As[128 * 64];
  __shared__ __align__(16) unsigned short Bs[128 * 64];
  const int m0 = blockIdx.x * 128, n0 = blockIdx.y * 128;
  const int tid = threadIdx.x;
  const int w = tid >> 6, lane = tid & 63, quad = lane >> 4, lc = lane & 15;
  const int wm = (w >> 1) * 64, wn = (w & 1) * 64;

  f32x4 acc[4][4] = {};
  gemm_core(A, W, m0, n0, 1024, As, Bs, acc);

#pragma unroll
  for (int j = 0; j < 4; j++) {
    int col = n0 + wn + j * 16 + lc;
    float bvl = bias[col];
#pragma unroll
    for (int i = 0; i < 4; i++)
#pragma unroll
      for (int r = 0; r < 4; r++) {
        int row = m0 + wm + i * 16 + quad * 4 + r;
        outf[(size_t)row * 1024 + col] = acc[i][j][r] + bvl;
      }
  }
}

// ---------------- fused attention: two-pass flash, K/V LDS-staged per 64-kv chunk ----
// grid (B*H=64, S/64=16), 4 waves; wave owns 16 q-rows. Chunk loop is block-uniform
// (nch = by+1), so barriers are safe; per-wave tile validity (tmax) is wave-uniform.
// Pass A: K staged via global_load_lds (XOR-granule swizzle), per-lane online (m,l).
// Pass B: K+V staged; recompute QK^T, p -> fp32 LDS tile -> coalesced float4 attn
// stores; p(bf16) -> wave-private LDS -> PV MFMA. O bounced via LDS to 16B stores.
__global__ __launch_bounds__(256) void attn_fused(
    const unsigned short* __restrict__ Qb,   // (B*S,E) bf16
    const unsigned short* __restrict__ Kb,   // (B*S,E) bf16
    const unsigned short* __restrict__ Vt,   // (B*H,HD,S) bf16
    float* __restrict__ attn,                // (B*H,S,S) fp32
    unsigned short* __restrict__ O)          // (B*S,E) bf16
{
  __shared__ __align__(16) unsigned short Ks[64 * 64];   // row kv-local; granule g at slot g^(r&7)
  __shared__ __align__(16) unsigned short Vs[64 * 64];   // row hd;       granule g at slot g^(r&7)
  __shared__ __align__(16) unsigned short Pl[4][16][40]; // per-wave bf16 P (32 kv), 80B stride
  __shared__ __align__(16) float          Ps[4][16][36]; // per-wave fp32 P (32 kv), 144B stride
  const int bh = blockIdx.x, b = bh >> 4, h = bh & 15;
  const int by = (int)gridDim.y - 1 - (int)blockIdx.y;   // heavy blocks dispatch first
  const int q0 = by * 64;
  const int tid = threadIdx.x;
  const int w = tid >> 6, lane = tid & 63, quad = lane >> 4, lc = lane & 15;
  const int g0 = q0 + w * 16;
  const int kt_d = g0 >> 4;                  // wave's diagonal 16-tile index = 4*by + w
  const int nch = by + 1;                    // 64-kv chunks (block-uniform)
  const int sr = lane >> 3, sg = lane & 7;   // staging coords: 8 rows x 8 granules per wave-load

  const unsigned short* qp = Qb + ((size_t)(b * 1024 + g0 + lc)) * 1024 + h * 64 + quad * 8;
  bf16x8 a0 = *(const bf16x8*)qp;
  bf16x8 a1 = *(const bf16x8*)(qp + 32);

  float m_[4] = { -1e30f, -1e30f, -1e30f, -1e30f };
  float l_[4] = { 0.f, 0.f, 0.f, 0.f };

  // ---- pass A: online stats; K staged once per chunk, shared by all 4 waves ----
  for (int c = 0; c < nch; c++) {
    int kv0 = c * 64;
    {
      int r0 = w * 8 + sr, r1 = 32 + r0;
      gload16(&Kb[((size_t)(b * 1024 + kv0 + r0)) * 1024 + h * 64 + (sg ^ (r0 & 7)) * 8],
              &Ks[(w * 8) * 64]);
      gload16(&Kb[((size_t)(b * 1024 + kv0 + r1)) * 1024 + h * 64 + (sg ^ (r1 & 7)) * 8],
              &Ks[(32 + w * 8) * 64]);
    }
    __syncthreads();
    int tmax = kt_d - c * 4;                 // >= 0 always (c <= by, kt_d >= 4*by+w)
    int tlim = tmax < 3 ? tmax : 3;
    for (int t = 0; t <= tlim; t++) {
      int rk = t * 16 + lc;
      const unsigned short* kr = &Ks[rk * 64];
      bf16x8 b0 = *(const bf16x8*)&kr[((quad ^ (rk & 7))) * 8];
      bf16x8 b1 = *(const bf16x8*)&kr[(((quad + 4) ^ (rk & 7))) * 8];
      f32x4 cc = {};
      cc = __builtin_amdgcn_mfma_f32_16x16x32_bf16(a0, b0, cc, 0, 0, 0);
      cc = __builtin_amdgcn_mfma_f32_16x16x32_bf16(a1, b1, cc, 0, 0, 0);
      if (t < tmax) {                        // strictly below diagonal: no mask needed
#pragma unroll
        for (int r = 0; r < 4; r++) {
          float s = cc[r] * 0.125f;
          float mn = fmaxf(m_[r], s);
          l_[r] = l_[r] * __expf(m_[r] - mn) + __expf(s - mn);
          m_[r] = mn;
        }
      } else {                               // diagonal tile: apply causal mask
#pragma unroll
        for (int r = 0; r < 4; r++) {
          int qr = g0 + quad * 4 + r;
          float sv = (kv0 + t * 16 + lc) > qr ? -1e30f : cc[r] * 0.125f;
          float mn = fmaxf(m_[r], sv);
          l_[r] = l_[r] * __expf(m_[r] - mn) + __expf(sv - mn);
          m_[r] = mn;
        }
      }
    }
    __syncthreads();
  }

  // one cross-lane reduction per row group (16 lanes share a row)
  float mofs[4];
#pragma unroll
  for (int r = 0; r < 4; r++) {
    float mT = m_[r];
#pragma unroll
    for (int off = 1; off < 16; off <<= 1) mT = fmaxf(mT, __shfl_xor(mT, off));
    float lt = l_[r] * __expf(m_[r] - mT);
#pragma unroll
    for (int off = 1; off < 16; off <<= 1) lt += __shfl_xor(lt, off);
    mofs[r] = mT + __logf(lt);               // p = exp(s - m - ln l)
  }

  // ---- pass B: recompute, normalize, coalesced attn stores, PV ----
  float* arow = attn + (size_t)bh * 1024 * 1024;
  f32x4 oacc[4] = {};
  for (int c = 0; c < nch; c++) {
    int kv0 = c * 64;
    {
      int r0 = w * 8 + sr, r1 = 32 + r0;
      gload16(&Kb[((size_t)(b * 1024 + kv0 + r0)) * 1024 + h * 64 + (sg ^ (r0 & 7)) * 8],
              &Ks[(w * 8) * 64]);
      gload16(&Kb[((size_t)(b * 1024 + kv0 + r1)) * 1024 + h * 64 + (sg ^ (r1 & 7)) * 8],
              &Ks[(32 + w * 8) * 64]);
      gload16(&Vt[((size_t)(bh * 64 + r0)) * 1024 + kv0 + (sg ^ (r0 & 7)) * 8],
              &Vs[(w * 8) * 64]);
      gload16(&Vt[((size_t)(bh * 64 + r1)) * 1024 + kv0 + (sg ^ (r1 & 7)) * 8],
              &Vs[(32 + w * 8) * 64]);
    }
    __syncthreads();
    int tmax = kt_d - c * 4;
#pragma unroll
    for (int u = 0; u < 2; u++) {
      if (u * 2 <= tmax) {                   // wave-uniform
#pragma unroll
        for (int t2 = 0; t2 < 2; t2++) {
          int t = u * 2 + t2;
          if (t <= tmax) {                   // wave-uniform
            int rk = t * 16 + lc;
            const unsigned short* kr = &Ks[rk * 64];
            bf16x8 b0 = *(const bf16x8*)&kr[((quad ^ (rk & 7))) * 8];
            bf16x8 b1 = *(const bf16x8*)&kr[(((quad + 4) ^ (rk & 7))) * 8];
            f32x4 cc = {};
            cc = __builtin_amdgcn_mfma_f32_16x16x32_bf16(a0, b0, cc, 0, 0, 0);
            cc = __builtin_amdgcn_mfma_f32_16x16x32_bf16(a1, b1, cc, 0, 0, 0);
#pragma unroll
            for (int r = 0; r < 4; r++) {
              int qr = g0 + quad * 4 + r;
              float p = (kv0 + t * 16 + lc) > qr ? 0.f : __expf(cc[r] * 0.125f - mofs[r]);
              Ps[w][quad * 4 + r][t2 * 16 + lc] = p;
              Pl[w][quad * 4 + r][t2 * 16 + lc] = f2bf(p);
            }
          } else {
#pragma unroll
            for (int r = 0; r < 4; r++) Pl[w][quad * 4 + r][t2 * 16 + lc] = 0;
          }
        }
        // PV over this 32-kv sub-chunk (wave-private LDS; in-order per-wave DS pipe)
        bf16x8 pa = *(const bf16x8*)&Pl[w][lc][quad * 8];
#pragma unroll
        for (int j = 0; j < 4; j++) {
          int hd = j * 16 + lc;
          bf16x8 bv = *(const bf16x8*)&Vs[hd * 64 + (((u * 4 + quad) ^ (hd & 7)) * 8)];
          oacc[j] = __builtin_amdgcn_mfma_f32_16x16x32_bf16(pa, bv, oacc[j], 0, 0, 0);
        }
        // coalesced float4 attn stores of valid cols (16 rows x nt*16 cols)
        int nt = tmax - u * 2 + 1; if (nt > 2) nt = 2;
        int srow = lane >> 2, cf = (lane & 3) * 4;
        float* dst = &arow[(size_t)(g0 + srow) * 1024 + kv0 + u * 32];
        *(float4*)(dst + cf) = *(const float4*)&Ps[w][srow][cf];
        if (nt == 2)
          *(float4*)(dst + 16 + cf) = *(const float4*)&Ps[w][srow][16 + cf];
      }
    }
    __syncthreads();
  }

  // ---- zero-fill fully-masked region [g0+16, 1024) for the wave's 16 rows ----
  // 8 lanes x float4 = 128B contiguous per row, 8 rows per instruction (was 64B/row).
  {
    int rr = lane >> 3, cl = lane & 7;
    float4 z = make_float4(0.f, 0.f, 0.f, 0.f);
#pragma unroll
    for (int half = 0; half < 2; half++) {
      float* rowp = &arow[(size_t)(g0 + half * 8 + rr) * 1024];
      for (int c0 = g0 + 16 + cl * 4; c0 < 1024; c0 += 32)
        *(float4*)(rowp + c0) = z;
    }
  }

  // ---- store O (B*S,E) bf16, heads merged, via LDS bounce (16B stores) ----
  {
    unsigned short* ob = (unsigned short*)&Ps[w][0][0];  // 16 rows x 72-short stride
#pragma unroll
    for (int j = 0; j < 4; j++)
#pragma unroll
      for (int r = 0; r < 4; r++)
        ob[(quad * 4 + r) * 72 + j * 16 + lc] = f2bf(oacc[j][r]);
#pragma unroll
    for (int it = 0; it < 2; it++) {
      int row = it * 8 + (lane >> 3), off = (lane & 7) * 8;
      *(bf16x8*)&O[((size_t)(b * 1024 + g0 + row)) * 1024 + h * 64 + off] =
          *(const bf16x8*)&ob[row * 72 + off];
    }
  }
}

extern "C" void kernel_launch(void* const* d_in, const int* in_sizes, int n_in,
                              void* d_out, int out_size, void* d_ws, size_t ws_size,
                              hipStream_t stream) {
  const float* query = (const float*)d_in[0];
  const float* key_t = (const float*)d_in[1];
  const float* value = (const float*)d_in[2];
  // d_in[3] = mask: causal tril, applied analytically
  const float* Wq = (const float*)d_in[4];
  const float* bq = (const float*)d_in[5];
  const float* Wk = (const float*)d_in[6];
  const float* bk = (const float*)d_in[7];
  const float* Wv = (const float*)d_in[8];
  const float* bv = (const float*)d_in[9];
  const float* Wo = (const float*)d_in[10];
  const float* bo = (const float*)d_in[11];

  unsigned short* Xq  = (unsigned short*)d_ws;
  unsigned short* Xk  = Xq  + 4194304;
  unsigned short* Xv  = Xk  + 4194304;
  unsigned short* Wqb = Xv  + 4194304;
  unsigned short* Wkb = Wqb + 1048576;
  unsigned short* Wvb = Wkb + 1048576;
  unsigned short* Wob = Wvb + 1048576;
  unsigned short* Qb  = Wob + 1048576;
  unsigned short* Kb  = Qb  + 4194304;
  unsigned short* Vtb = Kb  + 4194304;
  unsigned short* Ob  = Vtb + 4194304;

  float* outO = (float*)d_out;
  float* attn = outO + 4194304;

  cast3_k<<<dim3(2048, 3), 256, 0, stream>>>(query, key_t, value, Xq, Xk, Xv);
  cast4_k<<<dim3(512, 4), 256, 0, stream>>>(Wq, Wk, Wv, Wo, Wqb, Wkb, Wvb, Wob);

  gemm_qkv<<<dim3(32, 8, 3), 256, 0, stream>>>(Xq, Xk, Xv, Wqb, Wkb, Wvb,
                                               bq, bk, bv, Qb, Kb, Vtb);

  attn_fused<<<dim3(64, 16), 256, 0, stream>>>(Qb, Kb, Vtb, attn, Ob);

  gemm_out<<<dim3(32, 8), 256, 0, stream>>>(Ob, Wob, bo, outO);
}